// Round 5
// baseline (327.653 us; speedup 1.0000x reference)
//
#include <hip/hip_runtime.h>

#define NN 50000
#define NE 800000
#define DIN 256
#define F1 96
#define F2 48
#define F3 24
#define EPSL 1e-5f
#define NB 196    // ceil(NN/256)
#define BKN 32    // nodes per bucket
#define NBUK 1563 // ceil(NN/32)

using bf16x8 = __attribute__((ext_vector_type(8))) short;
using f32x4 = __attribute__((ext_vector_type(4))) float;

__device__ __forceinline__ unsigned short f2b(float f) {
    unsigned u = __float_as_uint(f);
    unsigned r = (u + 0x7FFF + ((u >> 16) & 1)) >> 16;
    return (unsigned short)r;
}
__device__ __forceinline__ float b2f(unsigned short h) {
    return __uint_as_float((unsigned)h << 16);
}
__device__ __forceinline__ float4 unpk(uint2 u) {
    float4 r;
    r.x = __uint_as_float(u.x << 16);
    r.y = __uint_as_float(u.x & 0xFFFF0000u);
    r.z = __uint_as_float(u.y << 16);
    r.w = __uint_as_float(u.y & 0xFFFF0000u);
    return r;
}

// ---------------- edge-index access (int32 or int64 storage) ----------------
__device__ __forceinline__ int ld_src(const int* __restrict__ ei, int is64, int e) {
    return is64 ? ei[2 * e] : ei[e];
}
__device__ __forceinline__ int ld_dst(const int* __restrict__ ei, int is64, int e) {
    return is64 ? ei[2 * NE + 2 * e] : ei[NE + e];
}

__global__ void k_detect(const int* __restrict__ ei, int* __restrict__ flag) {
    if (threadIdx.x == 0 && blockIdx.x == 0) {
        int zeros = 0;
        for (int i = 0; i < 64; i++)
            if (ei[2 * i + 1] == 0) zeros++;
        *flag = (zeros >= 60) ? 1 : 0;
    }
}

// ---------------- degree histogram ----------------
__global__ void k_hist(const int* __restrict__ ei, const int* __restrict__ flag,
                       int* __restrict__ cnt) {
    int e = blockIdx.x * blockDim.x + threadIdx.x;
    if (e < NE) {
        int is64 = *flag;
        atomicAdd(&cnt[ld_dst(ei, is64, e)], 1);
    }
}

// ---------------- scan (exclusive prefix over cnt -> rowstart) ----------------
__global__ void k_scan_reduce(const int* __restrict__ cnt, int* __restrict__ bsum) {
    __shared__ int s[256];
    int t = threadIdx.x;
    int i = blockIdx.x * 256 + t;
    s[t] = (i < NN) ? cnt[i] : 0;
    __syncthreads();
    for (int off = 128; off > 0; off >>= 1) {
        if (t < off) s[t] += s[t + off];
        __syncthreads();
    }
    if (t == 0) bsum[blockIdx.x] = s[0];
}

__global__ void k_scan_top(const int* __restrict__ bsum, int* __restrict__ bsumex,
                           int* __restrict__ rowstart) {
    __shared__ int s[256];
    int t = threadIdx.x;
    int v = (t < NB) ? bsum[t] : 0;
    s[t] = v;
    __syncthreads();
    for (int off = 1; off < 256; off <<= 1) {
        int x = (t >= off) ? s[t - off] : 0;
        __syncthreads();
        s[t] += x;
        __syncthreads();
    }
    if (t < NB) bsumex[t] = s[t] - v;
    if (t == NB - 1) rowstart[NN] = s[t];
}

// also produces dis[]
__global__ void k_scan_fin(const int* __restrict__ cnt, const int* __restrict__ bsumex,
                           int* __restrict__ rowstart, float* __restrict__ dis) {
    __shared__ int s[256];
    int t = threadIdx.x;
    int i = blockIdx.x * 256 + t;
    int v = (i < NN) ? cnt[i] : 0;
    s[t] = v;
    __syncthreads();
    for (int off = 1; off < 256; off <<= 1) {
        int x = (t >= off) ? s[t - off] : 0;
        __syncthreads();
        s[t] += x;
        __syncthreads();
    }
    if (i < NN) {
        rowstart[i] = bsumex[blockIdx.x] + s[t] - v;
        dis[i] = rsqrtf((float)v + 1.0f);
    }
}

// ------- bucketed CSR build: stage (append into bucket region) -------
__global__ void k_stage(const int* __restrict__ ei, const int* __restrict__ flag,
                        const int* __restrict__ rowstart, int* __restrict__ bkcur,
                        uint* __restrict__ csr) {
    int e = blockIdx.x * blockDim.x + threadIdx.x;
    if (e >= NE) return;
    int is64 = *flag;
    int d = ld_dst(ei, is64, e);
    int s = ld_src(ei, is64, e);
    int base = rowstart[d & ~(BKN - 1)];
    int pos = atomicAdd(&bkcur[d >> 5], 1);
    csr[base + pos] = ((uint)(d & (BKN - 1)) << 16) | (uint)s;
}

// ------- bucketed CSR build: in-place per-bucket sort by node -------
__global__ __launch_bounds__(256) void k_sortb(const int* __restrict__ rowstart,
                                               uint* __restrict__ csr) {
    __shared__ uint ent[3072];
    __shared__ int cur[BKN];
    __shared__ int sbase[BKN + 1];
    int b = blockIdx.x;
    int t = threadIdx.x;
    int n0 = b * BKN;
    if (t <= BKN) {
        int n = n0 + t;
        sbase[t] = rowstart[n > NN ? NN : n];
    }
    if (t < BKN) cur[t] = 0;
    __syncthreads();
    int base = sbase[0];
    int cnt = sbase[BKN] - base;
    if (cnt > 3072) cnt = 3072;  // statistically impossible; LDS safety
    for (int i = t; i < cnt; i += 256) ent[i] = csr[base + i];
    __syncthreads();
    for (int i = t; i < cnt; i += 256) {
        uint v = ent[i];
        int dl = v >> 16;
        int p = atomicAdd(&cur[dl], 1);
        csr[sbase[dl] + p] = v & 0xFFFFu;
    }
}

// ---------------- BN constants prep ----------------
__global__ void k_bnprep(const float* __restrict__ b1, const float* __restrict__ g1,
                         const float* __restrict__ bb1, const float* __restrict__ m1,
                         const float* __restrict__ v1, const float* __restrict__ b2,
                         const float* __restrict__ g2, const float* __restrict__ bb2,
                         const float* __restrict__ m2, const float* __restrict__ v2,
                         const float* __restrict__ b3, const float* __restrict__ g3,
                         const float* __restrict__ bb3, const float* __restrict__ m3,
                         const float* __restrict__ v3, float* __restrict__ sc,
                         float* __restrict__ sh) {
    int t = threadIdx.x;
    if (t < F1) {
        float s = g1[t] * rsqrtf(v1[t] + EPSL);
        sc[t] = s;
        sh[t] = bb1[t] - m1[t] * s + b1[t] * s;
    } else if (t < F1 + F2) {
        int f = t - F1;
        float s = g2[f] * rsqrtf(v2[f] + EPSL);
        sc[t] = s;
        sh[t] = bb2[f] - m2[f] * s + b2[f] * s;
    } else if (t < F1 + F2 + F3) {
        int f = t - F1 - F2;
        float s = g3[f] * rsqrtf(v3[f] + EPSL);
        sc[t] = s;
        sh[t] = bb3[f] - m3[f] * s + b3[f] * s;
    }
}

// ---------------- W1 -> hi/lo bf16 fragments in MFMA order ----------------
__global__ void k_prepW(const float* __restrict__ W1, ushort* __restrict__ Wh,
                        ushort* __restrict__ Wl) {
    int gid = blockIdx.x * 256 + threadIdx.x;
    if (gid >= 3072) return;
    int l = gid & 63;
    int sw = gid >> 6;
    int s = sw & 7;
    int w = sw >> 3;
    int col = w * 16 + (l & 15);
    int kbase = s * 32 + (l >> 4) * 8;
    ushort hi[8], lo[8];
#pragma unroll
    for (int j = 0; j < 8; j++) {
        float v = W1[(size_t)(kbase + j) * F1 + col];
        ushort h = f2b(v);
        hi[j] = h;
        lo[j] = f2b(v - b2f(h));
    }
    *(uint4*)&Wh[(size_t)gid * 8] = *(uint4*)hi;
    *(uint4*)&Wl[(size_t)gid * 8] = *(uint4*)lo;
}

// ------- GEMM1: fused LN(stats in-kernel) @ W1 via split-bf16 MFMA, ·dis ------
__global__ __launch_bounds__(384) void k_gemm1m(
    const float* __restrict__ x, const float* __restrict__ dis,
    const float* __restrict__ ln_g, const float* __restrict__ ln_b,
    const ushort* __restrict__ Wh, const ushort* __restrict__ Wl,
    ushort* __restrict__ outb) {
    __shared__ ushort Ah[1024 * 8];  // 16KB, xor-swizzled
    __shared__ ushort Al[1024 * 8];  // 16KB
    int tid = threadIdx.x;
    int l = tid & 63;
    int w = tid >> 6;
    int brow = blockIdx.x * 32;

    bf16x8 Bh[8], Bl[8];
#pragma unroll
    for (int s = 0; s < 8; s++) {
        int gid = (w * 8 + s) * 64 + l;
        Bh[s] = *(const bf16x8*)&Wh[(size_t)gid * 8];
        Bl[s] = *(const bf16x8*)&Wl[(size_t)gid * 8];
    }

    // staging: rows map to 32-lane groups -> LN stats via shfl reduce
    for (int t = tid; t < 1024; t += 384) {
        int r = t >> 5;
        int c = t & 31;
        int row = brow + r;
        float4 v0 = make_float4(0.f, 0.f, 0.f, 0.f), v1 = v0;
        if (row < NN) {
            const float4* xp = (const float4*)(x + (size_t)row * DIN + c * 8);
            v0 = xp[0];
            v1 = xp[1];
        }
        float s = v0.x + v0.y + v0.z + v0.w + v1.x + v1.y + v1.z + v1.w;
        float q = v0.x * v0.x + v0.y * v0.y + v0.z * v0.z + v0.w * v0.w +
                  v1.x * v1.x + v1.y * v1.y + v1.z * v1.z + v1.w * v1.w;
#pragma unroll
        for (int off = 1; off < 32; off <<= 1) {
            s += __shfl_xor(s, off);
            q += __shfl_xor(q, off);
        }
        float m = s * (1.f / 256.f);
        float rs = rsqrtf(q * (1.f / 256.f) - m * m + EPSL);
        ushort hi[8], lo[8];
        const float4* gp = (const float4*)(ln_g + c * 8);
        const float4* bp = (const float4*)(ln_b + c * 8);
        float4 g0 = gp[0], g1 = gp[1];
        float4 b0 = bp[0], b1 = bp[1];
        float vals[8];
        vals[0] = (v0.x - m) * rs * g0.x + b0.x;
        vals[1] = (v0.y - m) * rs * g0.y + b0.y;
        vals[2] = (v0.z - m) * rs * g0.z + b0.z;
        vals[3] = (v0.w - m) * rs * g0.w + b0.w;
        vals[4] = (v1.x - m) * rs * g1.x + b1.x;
        vals[5] = (v1.y - m) * rs * g1.y + b1.y;
        vals[6] = (v1.z - m) * rs * g1.z + b1.z;
        vals[7] = (v1.w - m) * rs * g1.w + b1.w;
#pragma unroll
        for (int j = 0; j < 8; j++) {
            ushort h = f2b(vals[j]);
            hi[j] = h;
            lo[j] = f2b(vals[j] - b2f(h));
        }
        int sidx = c >> 2, lh = c & 3, rg = r >> 4;
        int slot = (rg * 8 + sidx) * 64 + lh * 16 + (r & 15);
        int byte_off = (slot * 16) ^ ((c & 7) << 4);
        *(uint4*)((char*)Ah + byte_off) = *(uint4*)hi;
        *(uint4*)((char*)Al + byte_off) = *(uint4*)lo;
    }
    __syncthreads();

    f32x4 acc0 = {0.f, 0.f, 0.f, 0.f}, acc1 = {0.f, 0.f, 0.f, 0.f};
#pragma unroll
    for (int s = 0; s < 8; s++) {
        int key = ((s * 4 + (l >> 4)) & 7) << 4;
        int b0 = (((0 * 8 + s) * 64 + l) * 16) ^ key;
        int b1 = (((1 * 8 + s) * 64 + l) * 16) ^ key;
        bf16x8 ah0 = *(const bf16x8*)((const char*)Ah + b0);
        bf16x8 al0 = *(const bf16x8*)((const char*)Al + b0);
        bf16x8 ah1 = *(const bf16x8*)((const char*)Ah + b1);
        bf16x8 al1 = *(const bf16x8*)((const char*)Al + b1);
        acc0 = __builtin_amdgcn_mfma_f32_16x16x32_bf16(al0, Bh[s], acc0, 0, 0, 0);
        acc0 = __builtin_amdgcn_mfma_f32_16x16x32_bf16(ah0, Bl[s], acc0, 0, 0, 0);
        acc0 = __builtin_amdgcn_mfma_f32_16x16x32_bf16(ah0, Bh[s], acc0, 0, 0, 0);
        acc1 = __builtin_amdgcn_mfma_f32_16x16x32_bf16(al1, Bh[s], acc1, 0, 0, 0);
        acc1 = __builtin_amdgcn_mfma_f32_16x16x32_bf16(ah1, Bl[s], acc1, 0, 0, 0);
        acc1 = __builtin_amdgcn_mfma_f32_16x16x32_bf16(ah1, Bh[s], acc1, 0, 0, 0);
    }

    int colg = w * 16 + (l & 15);
    int rbase = (l >> 4) * 4;
#pragma unroll
    for (int i = 0; i < 4; i++) {
        int row0 = brow + rbase + i;
        if (row0 < NN) outb[(size_t)row0 * F1 + colg] = f2b(acc0[i] * dis[row0]);
        int row1 = brow + 16 + rbase + i;
        if (row1 < NN) outb[(size_t)row1 * F1 + colg] = f2b(acc1[i] * dis[row1]);
    }
}

// ---------------- GEMM2: a1[NN,96] @ W2[96,48] -> bf16·dis ----------------
__global__ __launch_bounds__(256) void k_gemm2(const float* __restrict__ A,
                                               const float* __restrict__ W,
                                               const float* __restrict__ dis,
                                               ushort* __restrict__ outb) {
    __shared__ float At[F1][68];
    __shared__ float Ws[F1][F2];
    int tid = threadIdx.x;
    int brow = blockIdx.x * 64;
#pragma unroll
    for (int i = 0; i < 24; i++) {
        int idx = tid + i * 256;
        int r = idx / F1;
        int kk = idx % F1;
        int row = brow + r;
        At[kk][r] = (row < NN) ? A[(size_t)row * F1 + kk] : 0.f;
    }
#pragma unroll
    for (int i = 0; i < 18; i++) {
        int idx = tid + i * 256;
        Ws[idx / F2][idx % F2] = W[idx];
    }
    __syncthreads();
    int rg = tid >> 4;
    int cg = tid & 15;
    float acc[4][3] = {};
#pragma unroll 4
    for (int k = 0; k < F1; k++) {
        float4 a = *(const float4*)&At[k][rg * 4];
        float b[3];
        b[0] = Ws[k][cg * 3];
        b[1] = Ws[k][cg * 3 + 1];
        b[2] = Ws[k][cg * 3 + 2];
#pragma unroll
        for (int j = 0; j < 3; j++) {
            acc[0][j] += a.x * b[j];
            acc[1][j] += a.y * b[j];
            acc[2][j] += a.z * b[j];
            acc[3][j] += a.w * b[j];
        }
    }
#pragma unroll
    for (int i = 0; i < 4; i++) {
        int row = brow + rg * 4 + i;
        if (row < NN) {
            float dsc = dis[row];
            ushort* o = outb + (size_t)row * F2 + cg * 3;
#pragma unroll
            for (int j = 0; j < 3; j++) o[j] = f2b(acc[i][j] * dsc);
        }
    }
}

// ---------------- GEMM3: a2[NN,48] @ W3[48,24] -> bf16·dis ----------------
__global__ __launch_bounds__(256) void k_gemm3(const float* __restrict__ A,
                                               const float* __restrict__ W,
                                               const float* __restrict__ dis,
                                               ushort* __restrict__ outb) {
    __shared__ float At[F2][132];
    __shared__ float Ws[F2][F3];
    int tid = threadIdx.x;
    int brow = blockIdx.x * 128;
#pragma unroll
    for (int i = 0; i < 24; i++) {
        int idx = tid + i * 256;
        int r = idx / F2;
        int kk = idx % F2;
        int row = brow + r;
        At[kk][r] = (row < NN) ? A[(size_t)row * F2 + kk] : 0.f;
    }
#pragma unroll
    for (int i = 0; i < 5; i++) {
        int idx = tid + i * 256;
        if (idx < F2 * F3) Ws[idx / F3][idx % F3] = W[idx];
    }
    __syncthreads();
    int rg = tid >> 3;
    int cg = tid & 7;
    float acc[4][3] = {};
#pragma unroll 4
    for (int k = 0; k < F2; k++) {
        float4 a = *(const float4*)&At[k][rg * 4];
        float b[3];
        b[0] = Ws[k][cg * 3];
        b[1] = Ws[k][cg * 3 + 1];
        b[2] = Ws[k][cg * 3 + 2];
#pragma unroll
        for (int j = 0; j < 3; j++) {
            acc[0][j] += a.x * b[j];
            acc[1][j] += a.y * b[j];
            acc[2][j] += a.z * b[j];
            acc[3][j] += a.w * b[j];
        }
    }
#pragma unroll
    for (int i = 0; i < 4; i++) {
        int row = brow + rg * 4 + i;
        if (row < NN) {
            float dsc = dis[row];
            ushort* o = outb + (size_t)row * F3 + cg * 3;
#pragma unroll
            for (int j = 0; j < 3; j++) o[j] = f2b(acc[i][j] * dsc);
        }
    }
}

// ----- CSR gather agg (bf16 pre-scaled src) + self + ·dis + BN + ReLU -----
template <int F4>
__global__ __launch_bounds__(256) void k_agg(const ushort* __restrict__ hb,
                                             const uint* __restrict__ csr,
                                             const int* __restrict__ rowstart,
                                             const float* __restrict__ dis,
                                             const float* __restrict__ bnsc,
                                             const float* __restrict__ bnsh,
                                             float4* __restrict__ hout) {
    int t = blockIdx.x * blockDim.x + threadIdx.x;
    if (t >= NN * F4) return;
    int n = t / F4;
    int q = t - n * F4;
    const uint2* hrow = (const uint2*)hb;
    int e0 = rowstart[n], e1 = rowstart[n + 1];
    float4 acc = make_float4(0.f, 0.f, 0.f, 0.f);
    int e = e0;
    for (; e + 4 <= e1; e += 4) {
        uint s0 = csr[e + 0], s1 = csr[e + 1], s2 = csr[e + 2], s3 = csr[e + 3];
        uint2 u0 = hrow[(size_t)s0 * F4 + q];
        uint2 u1 = hrow[(size_t)s1 * F4 + q];
        uint2 u2 = hrow[(size_t)s2 * F4 + q];
        uint2 u3 = hrow[(size_t)s3 * F4 + q];
        float4 h0 = unpk(u0), h1 = unpk(u1), h2 = unpk(u2), h3 = unpk(u3);
        acc.x += h0.x + h1.x + h2.x + h3.x;
        acc.y += h0.y + h1.y + h2.y + h3.y;
        acc.z += h0.z + h1.z + h2.z + h3.z;
        acc.w += h0.w + h1.w + h2.w + h3.w;
    }
    for (; e < e1; e++) {
        float4 hv = unpk(hrow[(size_t)csr[e] * F4 + q]);
        acc.x += hv.x;
        acc.y += hv.y;
        acc.z += hv.z;
        acc.w += hv.w;
    }
    float d = dis[n];
    float4 hs = unpk(hrow[(size_t)n * F4 + q]);
    float ax = (acc.x + hs.x) * d;
    float ay = (acc.y + hs.y) * d;
    float az = (acc.z + hs.z) * d;
    float aw = (acc.w + hs.w) * d;
    const float4 sc = *(const float4*)&bnsc[q * 4];
    const float4 sh = *(const float4*)&bnsh[q * 4];
    float4 o;
    o.x = fmaxf(ax * sc.x + sh.x, 0.f);
    o.y = fmaxf(ay * sc.y + sh.y, 0.f);
    o.z = fmaxf(az * sc.z + sh.z, 0.f);
    o.w = fmaxf(aw * sc.w + sh.w, 0.f);
    hout[t] = o;
}

// ---------------- classifier: fc1 + LN + relu + fc2 ----------------
__global__ __launch_bounds__(256) void k_cls(const float* __restrict__ h,
                                             const float* __restrict__ fc1W,
                                             const float* __restrict__ fc1b,
                                             const float* __restrict__ lng,
                                             const float* __restrict__ lnb,
                                             const float* __restrict__ fc2W,
                                             const float* __restrict__ fc2b,
                                             float* __restrict__ out) {
    __shared__ float sW1[24 * 12], sW2[12 * 8], sb1[12], sg[12], sb[12], sb2[8];
    int tid = threadIdx.x;
    for (int i = tid; i < 288; i += 256) sW1[i] = fc1W[i];
    if (tid < 96) sW2[tid] = fc2W[tid];
    if (tid < 12) {
        sb1[tid] = fc1b[tid];
        sg[tid] = lng[tid];
        sb[tid] = lnb[tid];
    }
    if (tid < 8) sb2[tid] = fc2b[tid];
    __syncthreads();
    int n = blockIdx.x * blockDim.x + tid;
    if (n >= NN) return;
    float hv[24];
    const float4* hp = (const float4*)(h + (size_t)n * 24);
#pragma unroll
    for (int i = 0; i < 6; i++) {
        float4 v = hp[i];
        hv[i * 4] = v.x;
        hv[i * 4 + 1] = v.y;
        hv[i * 4 + 2] = v.z;
        hv[i * 4 + 3] = v.w;
    }
    float z[12];
#pragma unroll
    for (int j = 0; j < 12; j++) {
        float a = sb1[j];
#pragma unroll
        for (int k = 0; k < 24; k++) a += hv[k] * sW1[k * 12 + j];
        z[j] = a;
    }
    float s = 0.f, q = 0.f;
#pragma unroll
    for (int j = 0; j < 12; j++) {
        s += z[j];
        q += z[j] * z[j];
    }
    float m = s * (1.f / 12.f);
    float var = q * (1.f / 12.f) - m * m;
    float rs = rsqrtf(var + EPSL);
#pragma unroll
    for (int j = 0; j < 12; j++) z[j] = fmaxf((z[j] - m) * rs * sg[j] + sb[j], 0.f);
    float o[8];
#pragma unroll
    for (int c = 0; c < 8; c++) {
        float a = sb2[c];
#pragma unroll
        for (int j = 0; j < 12; j++) a += z[j] * sW2[j * 8 + c];
        o[c] = a;
    }
    float4* op = (float4*)(out + (size_t)n * 8);
    op[0] = make_float4(o[0], o[1], o[2], o[3]);
    op[1] = make_float4(o[4], o[5], o[6], o[7]);
}

// ---------------- launch ----------------
extern "C" void kernel_launch(void* const* d_in, const int* in_sizes, int n_in,
                              void* d_out, int out_size, void* d_ws, size_t ws_size,
                              hipStream_t stream) {
    const float* x = (const float*)d_in[0];
    const int* ei = (const int*)d_in[1];
    const float* ln_g = (const float*)d_in[2];
    const float* ln_b = (const float*)d_in[3];
    const float* W1 = (const float*)d_in[4];
    const float* b1 = (const float*)d_in[5];
    const float* bn1_g = (const float*)d_in[6];
    const float* bn1_b = (const float*)d_in[7];
    const float* bn1_m = (const float*)d_in[8];
    const float* bn1_v = (const float*)d_in[9];
    const float* W2 = (const float*)d_in[10];
    const float* b2 = (const float*)d_in[11];
    const float* bn2_g = (const float*)d_in[12];
    const float* bn2_b = (const float*)d_in[13];
    const float* bn2_m = (const float*)d_in[14];
    const float* bn2_v = (const float*)d_in[15];
    const float* W3 = (const float*)d_in[16];
    const float* b3 = (const float*)d_in[17];
    const float* bn3_g = (const float*)d_in[18];
    const float* bn3_b = (const float*)d_in[19];
    const float* bn3_m = (const float*)d_in[20];
    const float* bn3_v = (const float*)d_in[21];
    const float* fc1_W = (const float*)d_in[22];
    const float* fc1_b = (const float*)d_in[23];
    const float* lnc_g = (const float*)d_in[24];
    const float* lnc_b = (const float*)d_in[25];
    const float* fc2_W = (const float*)d_in[26];
    const float* fc2_b = (const float*)d_in[27];

    char* w = (char*)d_ws;
    auto alloc = [&](size_t bytes) {
        char* p = w;
        w += (bytes + 255) & ~(size_t)255;
        return p;
    };
    int* flag = (int*)alloc(4);
    int* cnt = (int*)alloc(NN * 4);
    int* bkcur = (int*)alloc(NBUK * 4);
    int* bsum = (int*)alloc(1024);
    int* bsumex = (int*)alloc(1024);
    int* rowstart = (int*)alloc((NN + 1) * 4);
    float* dis = (float*)alloc(NN * 4);
    float* bnsc = (float*)alloc(1024);
    float* bnsh = (float*)alloc(1024);
    uint* csr = (uint*)alloc((size_t)NE * 4);
    float* bufA = (float*)alloc((size_t)NN * F1 * 4);  // fp32 agg outputs
    ushort* hb = (ushort*)alloc((size_t)NN * F1 * 2);  // bf16 gemm outputs (·dis)
    ushort* Wh = (ushort*)alloc(3072 * 8 * 2);
    ushort* Wl = (ushort*)alloc(3072 * 8 * 2);

    hipMemsetAsync(cnt, 0, NN * 4, stream);
    hipMemsetAsync(bkcur, 0, NBUK * 4, stream);
    k_detect<<<1, 64, 0, stream>>>(ei, flag);
    k_hist<<<(NE + 255) / 256, 256, 0, stream>>>(ei, flag, cnt);
    k_scan_reduce<<<NB, 256, 0, stream>>>(cnt, bsum);
    k_scan_top<<<1, 256, 0, stream>>>(bsum, bsumex, rowstart);
    k_scan_fin<<<NB, 256, 0, stream>>>(cnt, bsumex, rowstart, dis);
    k_stage<<<(NE + 255) / 256, 256, 0, stream>>>(ei, flag, rowstart, bkcur, csr);
    k_sortb<<<NBUK, 256, 0, stream>>>(rowstart, csr);
    k_bnprep<<<1, 256, 0, stream>>>(b1, bn1_g, bn1_b, bn1_m, bn1_v, b2, bn2_g, bn2_b,
                                    bn2_m, bn2_v, b3, bn3_g, bn3_b, bn3_m, bn3_v, bnsc,
                                    bnsh);
    k_prepW<<<12, 256, 0, stream>>>(W1, Wh, Wl);
    k_gemm1m<<<(NN + 31) / 32, 384, 0, stream>>>(x, dis, ln_g, ln_b, Wh, Wl, hb);
    k_agg<24><<<(NN * 24 + 255) / 256, 256, 0, stream>>>(hb, csr, rowstart, dis, bnsc,
                                                         bnsh, (float4*)bufA);
    k_gemm2<<<(NN + 63) / 64, 256, 0, stream>>>(bufA, W2, dis, hb);
    k_agg<12><<<(NN * 12 + 255) / 256, 256, 0, stream>>>(
        hb, csr, rowstart, dis, bnsc + F1, bnsh + F1, (float4*)bufA);
    k_gemm3<<<(NN + 127) / 128, 256, 0, stream>>>(bufA, W3, dis, hb);
    k_agg<6><<<(NN * 6 + 255) / 256, 256, 0, stream>>>(
        hb, csr, rowstart, dis, bnsc + F1 + F2, bnsh + F1 + F2, (float4*)bufA);
    k_cls<<<(NN + 255) / 256, 256, 0, stream>>>(bufA, fc1_W, fc1_b, lnc_g, lnc_b, fc2_W,
                                                fc2_b, (float*)d_out);
}

// Round 6
// 273.007 us; speedup vs baseline: 1.2002x; 1.2002x over previous
//
#include <hip/hip_runtime.h>

#define NN 50000
#define NE 800000
#define DIN 256
#define F1 96
#define F2 48
#define F3 24
#define EPSL 1e-5f
#define NB 196    // ceil(NN/256)
#define BKN 32    // nodes per bucket
#define NBUK 1563 // ceil(NN/32)
#define NSL 64    // cursor slices per bucket

using bf16x8 = __attribute__((ext_vector_type(8))) short;
using f32x4 = __attribute__((ext_vector_type(4))) float;

__device__ __forceinline__ unsigned short f2b(float f) {
    unsigned u = __float_as_uint(f);
    unsigned r = (u + 0x7FFF + ((u >> 16) & 1)) >> 16;
    return (unsigned short)r;
}
__device__ __forceinline__ float b2f(unsigned short h) {
    return __uint_as_float((unsigned)h << 16);
}
__device__ __forceinline__ float4 unpk(uint2 u) {
    float4 r;
    r.x = __uint_as_float(u.x << 16);
    r.y = __uint_as_float(u.x & 0xFFFF0000u);
    r.z = __uint_as_float(u.y << 16);
    r.w = __uint_as_float(u.y & 0xFFFF0000u);
    return r;
}

// ---------------- edge-index access (int32 or int64 storage) ----------------
__device__ __forceinline__ int ld_src(const int* __restrict__ ei, int is64, int e) {
    return is64 ? ei[2 * e] : ei[e];
}
__device__ __forceinline__ int ld_dst(const int* __restrict__ ei, int is64, int e) {
    return is64 ? ei[2 * NE + 2 * e] : ei[NE + e];
}

__global__ void k_detect(const int* __restrict__ ei, int* __restrict__ flag) {
    if (threadIdx.x == 0 && blockIdx.x == 0) {
        int zeros = 0;
        for (int i = 0; i < 64; i++)
            if (ei[2 * i + 1] == 0) zeros++;
        *flag = (zeros >= 60) ? 1 : 0;
    }
}

// ------- histogram: per-node counts + per-(bucket,slice) counts -------
__global__ void k_hist(const int* __restrict__ ei, const int* __restrict__ flag,
                       int* __restrict__ cnt, int* __restrict__ cnt2) {
    int e = blockIdx.x * blockDim.x + threadIdx.x;
    if (e < NE) {
        int is64 = *flag;
        int d = ld_dst(ei, is64, e);
        int sl = blockIdx.x & (NSL - 1);
        atomicAdd(&cnt[d], 1);
        atomicAdd(&cnt2[(d >> 5) * NSL + sl], 1);
    }
}

// ---------------- scan (exclusive prefix over cnt -> rowstart) ----------------
__global__ void k_scan_reduce(const int* __restrict__ cnt, int* __restrict__ bsum) {
    __shared__ int s[256];
    int t = threadIdx.x;
    int i = blockIdx.x * 256 + t;
    s[t] = (i < NN) ? cnt[i] : 0;
    __syncthreads();
    for (int off = 128; off > 0; off >>= 1) {
        if (t < off) s[t] += s[t + off];
        __syncthreads();
    }
    if (t == 0) bsum[blockIdx.x] = s[0];
}

__global__ void k_scan_top(const int* __restrict__ bsum, int* __restrict__ bsumex,
                           int* __restrict__ rowstart) {
    __shared__ int s[256];
    int t = threadIdx.x;
    int v = (t < NB) ? bsum[t] : 0;
    s[t] = v;
    __syncthreads();
    for (int off = 1; off < 256; off <<= 1) {
        int x = (t >= off) ? s[t - off] : 0;
        __syncthreads();
        s[t] += x;
        __syncthreads();
    }
    if (t < NB) bsumex[t] = s[t] - v;
    if (t == NB - 1) rowstart[NN] = s[t];
}

// also produces dis[]
__global__ void k_scan_fin(const int* __restrict__ cnt, const int* __restrict__ bsumex,
                           int* __restrict__ rowstart, float* __restrict__ dis) {
    __shared__ int s[256];
    int t = threadIdx.x;
    int i = blockIdx.x * 256 + t;
    int v = (i < NN) ? cnt[i] : 0;
    s[t] = v;
    __syncthreads();
    for (int off = 1; off < 256; off <<= 1) {
        int x = (t >= off) ? s[t - off] : 0;
        __syncthreads();
        s[t] += x;
        __syncthreads();
    }
    if (i < NN) {
        rowstart[i] = bsumex[blockIdx.x] + s[t] - v;
        dis[i] = rsqrtf((float)v + 1.0f);
    }
}

// ------- per-bucket scan of slice counts -> absolute slice cursors -------
__global__ __launch_bounds__(64) void k_scan2(const int* __restrict__ rowstart,
                                              int* __restrict__ cnt2) {
    int b = blockIdx.x;
    int t = threadIdx.x;
    int v = cnt2[b * NSL + t];
    int inc = v;
#pragma unroll
    for (int off = 1; off < NSL; off <<= 1) {
        int u = __shfl_up(inc, off, 64);
        if (t >= off) inc += u;
    }
    cnt2[b * NSL + t] = rowstart[b * BKN] + inc - v;
}

// ------- scatter into bucket region using slice-private cursors -------
__global__ void k_scatter(const int* __restrict__ ei, const int* __restrict__ flag,
                          int* __restrict__ cnt2, uint* __restrict__ csr) {
    int e = blockIdx.x * blockDim.x + threadIdx.x;
    if (e >= NE) return;
    int is64 = *flag;
    int d = ld_dst(ei, is64, e);
    int s = ld_src(ei, is64, e);
    int sl = blockIdx.x & (NSL - 1);
    int pos = atomicAdd(&cnt2[(d >> 5) * NSL + sl], 1);
    csr[pos] = ((uint)(d & (BKN - 1)) << 16) | (uint)s;
}

// ------- in-place per-bucket compaction to exact per-node order -------
__global__ __launch_bounds__(256) void k_sortb(const int* __restrict__ rowstart,
                                               uint* __restrict__ csr) {
    __shared__ uint ent[3072];
    __shared__ int cur[BKN];
    __shared__ int sbase[BKN + 1];
    int b = blockIdx.x;
    int t = threadIdx.x;
    int n0 = b * BKN;
    if (t <= BKN) {
        int n = n0 + t;
        sbase[t] = rowstart[n > NN ? NN : n];
    }
    if (t < BKN) cur[t] = 0;
    __syncthreads();
    int base = sbase[0];
    int cnt = sbase[BKN] - base;
    if (cnt > 3072) cnt = 3072;  // statistically impossible; LDS safety
    for (int i = t; i < cnt; i += 256) ent[i] = csr[base + i];
    __syncthreads();
    for (int i = t; i < cnt; i += 256) {
        uint v = ent[i];
        int dl = v >> 16;
        int p = atomicAdd(&cur[dl], 1);
        csr[sbase[dl] + p] = v & 0xFFFFu;
    }
}

// ---------------- BN constants prep ----------------
__global__ void k_bnprep(const float* __restrict__ b1, const float* __restrict__ g1,
                         const float* __restrict__ bb1, const float* __restrict__ m1,
                         const float* __restrict__ v1, const float* __restrict__ b2,
                         const float* __restrict__ g2, const float* __restrict__ bb2,
                         const float* __restrict__ m2, const float* __restrict__ v2,
                         const float* __restrict__ b3, const float* __restrict__ g3,
                         const float* __restrict__ bb3, const float* __restrict__ m3,
                         const float* __restrict__ v3, float* __restrict__ sc,
                         float* __restrict__ sh) {
    int t = threadIdx.x;
    if (t < F1) {
        float s = g1[t] * rsqrtf(v1[t] + EPSL);
        sc[t] = s;
        sh[t] = bb1[t] - m1[t] * s + b1[t] * s;
    } else if (t < F1 + F2) {
        int f = t - F1;
        float s = g2[f] * rsqrtf(v2[f] + EPSL);
        sc[t] = s;
        sh[t] = bb2[f] - m2[f] * s + b2[f] * s;
    } else if (t < F1 + F2 + F3) {
        int f = t - F1 - F2;
        float s = g3[f] * rsqrtf(v3[f] + EPSL);
        sc[t] = s;
        sh[t] = bb3[f] - m3[f] * s + b3[f] * s;
    }
}

// ---------------- W1 -> hi/lo bf16 fragments in MFMA order ----------------
__global__ void k_prepW(const float* __restrict__ W1, ushort* __restrict__ Wh,
                        ushort* __restrict__ Wl) {
    int gid = blockIdx.x * 256 + threadIdx.x;
    if (gid >= 3072) return;
    int l = gid & 63;
    int sw = gid >> 6;
    int s = sw & 7;
    int w = sw >> 3;
    int col = w * 16 + (l & 15);
    int kbase = s * 32 + (l >> 4) * 8;
    ushort hi[8], lo[8];
#pragma unroll
    for (int j = 0; j < 8; j++) {
        float v = W1[(size_t)(kbase + j) * F1 + col];
        ushort h = f2b(v);
        hi[j] = h;
        lo[j] = f2b(v - b2f(h));
    }
    *(uint4*)&Wh[(size_t)gid * 8] = *(uint4*)hi;
    *(uint4*)&Wl[(size_t)gid * 8] = *(uint4*)lo;
}

// ------- GEMM1: fused LN(stats in-kernel) @ W1 via split-bf16 MFMA, ·dis ------
__global__ __launch_bounds__(384) void k_gemm1m(
    const float* __restrict__ x, const float* __restrict__ dis,
    const float* __restrict__ ln_g, const float* __restrict__ ln_b,
    const ushort* __restrict__ Wh, const ushort* __restrict__ Wl,
    ushort* __restrict__ outb) {
    __shared__ ushort Ah[1024 * 8];  // 16KB, xor-swizzled
    __shared__ ushort Al[1024 * 8];  // 16KB
    int tid = threadIdx.x;
    int l = tid & 63;
    int w = tid >> 6;
    int brow = blockIdx.x * 32;

    bf16x8 Bh[8], Bl[8];
#pragma unroll
    for (int s = 0; s < 8; s++) {
        int gid = (w * 8 + s) * 64 + l;
        Bh[s] = *(const bf16x8*)&Wh[(size_t)gid * 8];
        Bl[s] = *(const bf16x8*)&Wl[(size_t)gid * 8];
    }

    // staging: rows map to 32-lane groups -> LN stats via shfl reduce
    for (int t = tid; t < 1024; t += 384) {
        int r = t >> 5;
        int c = t & 31;
        int row = brow + r;
        float4 v0 = make_float4(0.f, 0.f, 0.f, 0.f), v1 = v0;
        if (row < NN) {
            const float4* xp = (const float4*)(x + (size_t)row * DIN + c * 8);
            v0 = xp[0];
            v1 = xp[1];
        }
        float s = v0.x + v0.y + v0.z + v0.w + v1.x + v1.y + v1.z + v1.w;
        float q = v0.x * v0.x + v0.y * v0.y + v0.z * v0.z + v0.w * v0.w +
                  v1.x * v1.x + v1.y * v1.y + v1.z * v1.z + v1.w * v1.w;
#pragma unroll
        for (int off = 1; off < 32; off <<= 1) {
            s += __shfl_xor(s, off);
            q += __shfl_xor(q, off);
        }
        float m = s * (1.f / 256.f);
        float rs = rsqrtf(q * (1.f / 256.f) - m * m + EPSL);
        ushort hi[8], lo[8];
        const float4* gp = (const float4*)(ln_g + c * 8);
        const float4* bp = (const float4*)(ln_b + c * 8);
        float4 g0 = gp[0], g1 = gp[1];
        float4 b0 = bp[0], b1 = bp[1];
        float vals[8];
        vals[0] = (v0.x - m) * rs * g0.x + b0.x;
        vals[1] = (v0.y - m) * rs * g0.y + b0.y;
        vals[2] = (v0.z - m) * rs * g0.z + b0.z;
        vals[3] = (v0.w - m) * rs * g0.w + b0.w;
        vals[4] = (v1.x - m) * rs * g1.x + b1.x;
        vals[5] = (v1.y - m) * rs * g1.y + b1.y;
        vals[6] = (v1.z - m) * rs * g1.z + b1.z;
        vals[7] = (v1.w - m) * rs * g1.w + b1.w;
#pragma unroll
        for (int j = 0; j < 8; j++) {
            ushort h = f2b(vals[j]);
            hi[j] = h;
            lo[j] = f2b(vals[j] - b2f(h));
        }
        int sidx = c >> 2, lh = c & 3, rg = r >> 4;
        int slot = (rg * 8 + sidx) * 64 + lh * 16 + (r & 15);
        int byte_off = (slot * 16) ^ ((c & 7) << 4);
        *(uint4*)((char*)Ah + byte_off) = *(uint4*)hi;
        *(uint4*)((char*)Al + byte_off) = *(uint4*)lo;
    }
    __syncthreads();

    f32x4 acc0 = {0.f, 0.f, 0.f, 0.f}, acc1 = {0.f, 0.f, 0.f, 0.f};
#pragma unroll
    for (int s = 0; s < 8; s++) {
        int key = ((s * 4 + (l >> 4)) & 7) << 4;
        int b0 = (((0 * 8 + s) * 64 + l) * 16) ^ key;
        int b1 = (((1 * 8 + s) * 64 + l) * 16) ^ key;
        bf16x8 ah0 = *(const bf16x8*)((const char*)Ah + b0);
        bf16x8 al0 = *(const bf16x8*)((const char*)Al + b0);
        bf16x8 ah1 = *(const bf16x8*)((const char*)Ah + b1);
        bf16x8 al1 = *(const bf16x8*)((const char*)Al + b1);
        acc0 = __builtin_amdgcn_mfma_f32_16x16x32_bf16(al0, Bh[s], acc0, 0, 0, 0);
        acc0 = __builtin_amdgcn_mfma_f32_16x16x32_bf16(ah0, Bl[s], acc0, 0, 0, 0);
        acc0 = __builtin_amdgcn_mfma_f32_16x16x32_bf16(ah0, Bh[s], acc0, 0, 0, 0);
        acc1 = __builtin_amdgcn_mfma_f32_16x16x32_bf16(al1, Bh[s], acc1, 0, 0, 0);
        acc1 = __builtin_amdgcn_mfma_f32_16x16x32_bf16(ah1, Bl[s], acc1, 0, 0, 0);
        acc1 = __builtin_amdgcn_mfma_f32_16x16x32_bf16(ah1, Bh[s], acc1, 0, 0, 0);
    }

    int colg = w * 16 + (l & 15);
    int rbase = (l >> 4) * 4;
#pragma unroll
    for (int i = 0; i < 4; i++) {
        int row0 = brow + rbase + i;
        if (row0 < NN) outb[(size_t)row0 * F1 + colg] = f2b(acc0[i] * dis[row0]);
        int row1 = brow + 16 + rbase + i;
        if (row1 < NN) outb[(size_t)row1 * F1 + colg] = f2b(acc1[i] * dis[row1]);
    }
}

// ---------------- GEMM2: a1[NN,96] @ W2[96,48] -> bf16·dis ----------------
__global__ __launch_bounds__(256) void k_gemm2(const float* __restrict__ A,
                                               const float* __restrict__ W,
                                               const float* __restrict__ dis,
                                               ushort* __restrict__ outb) {
    __shared__ float At[F1][68];
    __shared__ float Ws[F1][F2];
    int tid = threadIdx.x;
    int brow = blockIdx.x * 64;
#pragma unroll
    for (int i = 0; i < 24; i++) {
        int idx = tid + i * 256;
        int r = idx / F1;
        int kk = idx % F1;
        int row = brow + r;
        At[kk][r] = (row < NN) ? A[(size_t)row * F1 + kk] : 0.f;
    }
#pragma unroll
    for (int i = 0; i < 18; i++) {
        int idx = tid + i * 256;
        Ws[idx / F2][idx % F2] = W[idx];
    }
    __syncthreads();
    int rg = tid >> 4;
    int cg = tid & 15;
    float acc[4][3] = {};
#pragma unroll 4
    for (int k = 0; k < F1; k++) {
        float4 a = *(const float4*)&At[k][rg * 4];
        float b[3];
        b[0] = Ws[k][cg * 3];
        b[1] = Ws[k][cg * 3 + 1];
        b[2] = Ws[k][cg * 3 + 2];
#pragma unroll
        for (int j = 0; j < 3; j++) {
            acc[0][j] += a.x * b[j];
            acc[1][j] += a.y * b[j];
            acc[2][j] += a.z * b[j];
            acc[3][j] += a.w * b[j];
        }
    }
#pragma unroll
    for (int i = 0; i < 4; i++) {
        int row = brow + rg * 4 + i;
        if (row < NN) {
            float dsc = dis[row];
            ushort* o = outb + (size_t)row * F2 + cg * 3;
#pragma unroll
            for (int j = 0; j < 3; j++) o[j] = f2b(acc[i][j] * dsc);
        }
    }
}

// ---------------- GEMM3: a2[NN,48] @ W3[48,24] -> bf16·dis ----------------
__global__ __launch_bounds__(256) void k_gemm3(const float* __restrict__ A,
                                               const float* __restrict__ W,
                                               const float* __restrict__ dis,
                                               ushort* __restrict__ outb) {
    __shared__ float At[F2][132];
    __shared__ float Ws[F2][F3];
    int tid = threadIdx.x;
    int brow = blockIdx.x * 128;
#pragma unroll
    for (int i = 0; i < 24; i++) {
        int idx = tid + i * 256;
        int r = idx / F2;
        int kk = idx % F2;
        int row = brow + r;
        At[kk][r] = (row < NN) ? A[(size_t)row * F2 + kk] : 0.f;
    }
#pragma unroll
    for (int i = 0; i < 5; i++) {
        int idx = tid + i * 256;
        if (idx < F2 * F3) Ws[idx / F3][idx % F3] = W[idx];
    }
    __syncthreads();
    int rg = tid >> 3;
    int cg = tid & 7;
    float acc[4][3] = {};
#pragma unroll 4
    for (int k = 0; k < F2; k++) {
        float4 a = *(const float4*)&At[k][rg * 4];
        float b[3];
        b[0] = Ws[k][cg * 3];
        b[1] = Ws[k][cg * 3 + 1];
        b[2] = Ws[k][cg * 3 + 2];
#pragma unroll
        for (int j = 0; j < 3; j++) {
            acc[0][j] += a.x * b[j];
            acc[1][j] += a.y * b[j];
            acc[2][j] += a.z * b[j];
            acc[3][j] += a.w * b[j];
        }
    }
#pragma unroll
    for (int i = 0; i < 4; i++) {
        int row = brow + rg * 4 + i;
        if (row < NN) {
            float dsc = dis[row];
            ushort* o = outb + (size_t)row * F3 + cg * 3;
#pragma unroll
            for (int j = 0; j < 3; j++) o[j] = f2b(acc[i][j] * dsc);
        }
    }
}

// ----- CSR gather agg (bf16 pre-scaled src) + self + ·dis + BN + ReLU -----
template <int F4>
__global__ __launch_bounds__(256) void k_agg(const ushort* __restrict__ hb,
                                             const uint* __restrict__ csr,
                                             const int* __restrict__ rowstart,
                                             const float* __restrict__ dis,
                                             const float* __restrict__ bnsc,
                                             const float* __restrict__ bnsh,
                                             float4* __restrict__ hout) {
    int t = blockIdx.x * blockDim.x + threadIdx.x;
    if (t >= NN * F4) return;
    int n = t / F4;
    int q = t - n * F4;
    const uint2* hrow = (const uint2*)hb;
    int e0 = rowstart[n], e1 = rowstart[n + 1];
    float4 acc = make_float4(0.f, 0.f, 0.f, 0.f);
    int e = e0;
    for (; e + 4 <= e1; e += 4) {
        uint s0 = csr[e + 0], s1 = csr[e + 1], s2 = csr[e + 2], s3 = csr[e + 3];
        uint2 u0 = hrow[(size_t)s0 * F4 + q];
        uint2 u1 = hrow[(size_t)s1 * F4 + q];
        uint2 u2 = hrow[(size_t)s2 * F4 + q];
        uint2 u3 = hrow[(size_t)s3 * F4 + q];
        float4 h0 = unpk(u0), h1 = unpk(u1), h2 = unpk(u2), h3 = unpk(u3);
        acc.x += h0.x + h1.x + h2.x + h3.x;
        acc.y += h0.y + h1.y + h2.y + h3.y;
        acc.z += h0.z + h1.z + h2.z + h3.z;
        acc.w += h0.w + h1.w + h2.w + h3.w;
    }
    for (; e < e1; e++) {
        float4 hv = unpk(hrow[(size_t)csr[e] * F4 + q]);
        acc.x += hv.x;
        acc.y += hv.y;
        acc.z += hv.z;
        acc.w += hv.w;
    }
    float d = dis[n];
    float4 hs = unpk(hrow[(size_t)n * F4 + q]);
    float ax = (acc.x + hs.x) * d;
    float ay = (acc.y + hs.y) * d;
    float az = (acc.z + hs.z) * d;
    float aw = (acc.w + hs.w) * d;
    const float4 sc = *(const float4*)&bnsc[q * 4];
    const float4 sh = *(const float4*)&bnsh[q * 4];
    float4 o;
    o.x = fmaxf(ax * sc.x + sh.x, 0.f);
    o.y = fmaxf(ay * sc.y + sh.y, 0.f);
    o.z = fmaxf(az * sc.z + sh.z, 0.f);
    o.w = fmaxf(aw * sc.w + sh.w, 0.f);
    hout[t] = o;
}

// ---------------- classifier: fc1 + LN + relu + fc2 ----------------
__global__ __launch_bounds__(256) void k_cls(const float* __restrict__ h,
                                             const float* __restrict__ fc1W,
                                             const float* __restrict__ fc1b,
                                             const float* __restrict__ lng,
                                             const float* __restrict__ lnb,
                                             const float* __restrict__ fc2W,
                                             const float* __restrict__ fc2b,
                                             float* __restrict__ out) {
    __shared__ float sW1[24 * 12], sW2[12 * 8], sb1[12], sg[12], sb[12], sb2[8];
    int tid = threadIdx.x;
    for (int i = tid; i < 288; i += 256) sW1[i] = fc1W[i];
    if (tid < 96) sW2[tid] = fc2W[tid];
    if (tid < 12) {
        sb1[tid] = fc1b[tid];
        sg[tid] = lng[tid];
        sb[tid] = lnb[tid];
    }
    if (tid < 8) sb2[tid] = fc2b[tid];
    __syncthreads();
    int n = blockIdx.x * blockDim.x + tid;
    if (n >= NN) return;
    float hv[24];
    const float4* hp = (const float4*)(h + (size_t)n * 24);
#pragma unroll
    for (int i = 0; i < 6; i++) {
        float4 v = hp[i];
        hv[i * 4] = v.x;
        hv[i * 4 + 1] = v.y;
        hv[i * 4 + 2] = v.z;
        hv[i * 4 + 3] = v.w;
    }
    float z[12];
#pragma unroll
    for (int j = 0; j < 12; j++) {
        float a = sb1[j];
#pragma unroll
        for (int k = 0; k < 24; k++) a += hv[k] * sW1[k * 12 + j];
        z[j] = a;
    }
    float s = 0.f, q = 0.f;
#pragma unroll
    for (int j = 0; j < 12; j++) {
        s += z[j];
        q += z[j] * z[j];
    }
    float m = s * (1.f / 12.f);
    float var = q * (1.f / 12.f) - m * m;
    float rs = rsqrtf(var + EPSL);
#pragma unroll
    for (int j = 0; j < 12; j++) z[j] = fmaxf((z[j] - m) * rs * sg[j] + sb[j], 0.f);
    float o[8];
#pragma unroll
    for (int c = 0; c < 8; c++) {
        float a = sb2[c];
#pragma unroll
        for (int j = 0; j < 12; j++) a += z[j] * sW2[j * 8 + c];
        o[c] = a;
    }
    float4* op = (float4*)(out + (size_t)n * 8);
    op[0] = make_float4(o[0], o[1], o[2], o[3]);
    op[1] = make_float4(o[4], o[5], o[6], o[7]);
}

// ---------------- launch ----------------
extern "C" void kernel_launch(void* const* d_in, const int* in_sizes, int n_in,
                              void* d_out, int out_size, void* d_ws, size_t ws_size,
                              hipStream_t stream) {
    const float* x = (const float*)d_in[0];
    const int* ei = (const int*)d_in[1];
    const float* ln_g = (const float*)d_in[2];
    const float* ln_b = (const float*)d_in[3];
    const float* W1 = (const float*)d_in[4];
    const float* b1 = (const float*)d_in[5];
    const float* bn1_g = (const float*)d_in[6];
    const float* bn1_b = (const float*)d_in[7];
    const float* bn1_m = (const float*)d_in[8];
    const float* bn1_v = (const float*)d_in[9];
    const float* W2 = (const float*)d_in[10];
    const float* b2 = (const float*)d_in[11];
    const float* bn2_g = (const float*)d_in[12];
    const float* bn2_b = (const float*)d_in[13];
    const float* bn2_m = (const float*)d_in[14];
    const float* bn2_v = (const float*)d_in[15];
    const float* W3 = (const float*)d_in[16];
    const float* b3 = (const float*)d_in[17];
    const float* bn3_g = (const float*)d_in[18];
    const float* bn3_b = (const float*)d_in[19];
    const float* bn3_m = (const float*)d_in[20];
    const float* bn3_v = (const float*)d_in[21];
    const float* fc1_W = (const float*)d_in[22];
    const float* fc1_b = (const float*)d_in[23];
    const float* lnc_g = (const float*)d_in[24];
    const float* lnc_b = (const float*)d_in[25];
    const float* fc2_W = (const float*)d_in[26];
    const float* fc2_b = (const float*)d_in[27];

    char* w = (char*)d_ws;
    auto alloc = [&](size_t bytes) {
        char* p = w;
        w += (bytes + 255) & ~(size_t)255;
        return p;
    };
    int* flag = (int*)alloc(4);
    int* cnt = (int*)alloc(NN * 4);
    int* cnt2 = (int*)alloc((size_t)NBUK * NSL * 4);  // 400KB slice cursors
    int* bsum = (int*)alloc(1024);
    int* bsumex = (int*)alloc(1024);
    int* rowstart = (int*)alloc((NN + 1) * 4);
    float* dis = (float*)alloc(NN * 4);
    float* bnsc = (float*)alloc(1024);
    float* bnsh = (float*)alloc(1024);
    uint* csr = (uint*)alloc((size_t)NE * 4);
    float* bufA = (float*)alloc((size_t)NN * F1 * 4);  // fp32 agg outputs
    ushort* hb = (ushort*)alloc((size_t)NN * F1 * 2);  // bf16 gemm outputs (·dis)
    ushort* Wh = (ushort*)alloc(3072 * 8 * 2);
    ushort* Wl = (ushort*)alloc(3072 * 8 * 2);

    hipMemsetAsync(cnt, 0, NN * 4, stream);
    hipMemsetAsync(cnt2, 0, (size_t)NBUK * NSL * 4, stream);
    k_detect<<<1, 64, 0, stream>>>(ei, flag);
    k_hist<<<(NE + 255) / 256, 256, 0, stream>>>(ei, flag, cnt, cnt2);
    k_scan_reduce<<<NB, 256, 0, stream>>>(cnt, bsum);
    k_scan_top<<<1, 256, 0, stream>>>(bsum, bsumex, rowstart);
    k_scan_fin<<<NB, 256, 0, stream>>>(cnt, bsumex, rowstart, dis);
    k_scan2<<<NBUK, 64, 0, stream>>>(rowstart, cnt2);
    k_scatter<<<(NE + 255) / 256, 256, 0, stream>>>(ei, flag, cnt2, csr);
    k_sortb<<<NBUK, 256, 0, stream>>>(rowstart, csr);
    k_bnprep<<<1, 256, 0, stream>>>(b1, bn1_g, bn1_b, bn1_m, bn1_v, b2, bn2_g, bn2_b,
                                    bn2_m, bn2_v, b3, bn3_g, bn3_b, bn3_m, bn3_v, bnsc,
                                    bnsh);
    k_prepW<<<12, 256, 0, stream>>>(W1, Wh, Wl);
    k_gemm1m<<<(NN + 31) / 32, 384, 0, stream>>>(x, dis, ln_g, ln_b, Wh, Wl, hb);
    k_agg<24><<<(NN * 24 + 255) / 256, 256, 0, stream>>>(hb, csr, rowstart, dis, bnsc,
                                                         bnsh, (float4*)bufA);
    k_gemm2<<<(NN + 63) / 64, 256, 0, stream>>>(bufA, W2, dis, hb);
    k_agg<12><<<(NN * 12 + 255) / 256, 256, 0, stream>>>(
        hb, csr, rowstart, dis, bnsc + F1, bnsh + F1, (float4*)bufA);
    k_gemm3<<<(NN + 127) / 128, 256, 0, stream>>>(bufA, W3, dis, hb);
    k_agg<6><<<(NN * 6 + 255) / 256, 256, 0, stream>>>(
        hb, csr, rowstart, dis, bnsc + F1 + F2, bnsh + F1 + F2, (float4*)bufA);
    k_cls<<<(NN + 255) / 256, 256, 0, stream>>>(bufA, fc1_W, fc1_b, lnc_g, lnc_b, fc2_W,
                                                fc2_b, (float*)d_out);
}

// Round 7
// 177.037 us; speedup vs baseline: 1.8508x; 1.5421x over previous
//
#include <hip/hip_runtime.h>

#define NN 50000
#define NE 800000
#define DIN 256
#define F1 96
#define F2 48
#define F3 24
#define EPSL 1e-5f
#define BKN 256     // nodes per bucket
#define NBUK 196    // ceil(NN/256)
#define SB 256      // scatter/hist blocks
#define EPB 3125    // edges per block (SB*EPB == NE exactly)
#define SORTCAP 6144

using bf16x8 = __attribute__((ext_vector_type(8))) short;
using f32x4 = __attribute__((ext_vector_type(4))) float;

__device__ __forceinline__ unsigned short f2b(float f) {
    unsigned u = __float_as_uint(f);
    unsigned r = (u + 0x7FFF + ((u >> 16) & 1)) >> 16;
    return (unsigned short)r;
}
__device__ __forceinline__ float b2f(unsigned short h) {
    return __uint_as_float((unsigned)h << 16);
}
__device__ __forceinline__ float4 unpk(uint2 u) {
    float4 r;
    r.x = __uint_as_float(u.x << 16);
    r.y = __uint_as_float(u.x & 0xFFFF0000u);
    r.z = __uint_as_float(u.y << 16);
    r.w = __uint_as_float(u.y & 0xFFFF0000u);
    return r;
}

// ---------------- edge-index access (int32 or int64 storage) ----------------
__device__ __forceinline__ int ld_src(const int* __restrict__ ei, int is64, int e) {
    return is64 ? ei[2 * e] : ei[e];
}
__device__ __forceinline__ int ld_dst(const int* __restrict__ ei, int is64, int e) {
    return is64 ? ei[2 * NE + 2 * e] : ei[NE + e];
}

__global__ void k_detect(const int* __restrict__ ei, int* __restrict__ flag) {
    if (threadIdx.x == 0 && blockIdx.x == 0) {
        int zeros = 0;
        for (int i = 0; i < 64; i++)
            if (ei[2 * i + 1] == 0) zeros++;
        *flag = (zeros >= 60) ? 1 : 0;
    }
}

// ------- per-block LDS bucket histogram (no global atomics) -------
__global__ __launch_bounds__(512) void k_histB(const int* __restrict__ ei,
                                               const int* __restrict__ flag,
                                               int* __restrict__ bh) {
    __shared__ int hist[NBUK];
    int blk = blockIdx.x, t = threadIdx.x;
    for (int i = t; i < NBUK; i += 512) hist[i] = 0;
    __syncthreads();
    int is64 = *flag;
    int e0 = blk * EPB;
    for (int i = t; i < EPB; i += 512) {
        int d = ld_dst(ei, is64, e0 + i);
        atomicAdd(&hist[d >> 8], 1);
    }
    __syncthreads();
    for (int i = t; i < NBUK; i += 512) bh[blk * NBUK + i] = hist[i];
}

// ------- bucket totals: bt[b] = sum over blocks of bh[blk][b] -------
__global__ __launch_bounds__(256) void k_scanB1(const int* __restrict__ bh,
                                                int* __restrict__ bt) {
    __shared__ int s[256];
    int b = blockIdx.x, t = threadIdx.x;
    s[t] = bh[t * NBUK + b];
    __syncthreads();
    for (int off = 128; off > 0; off >>= 1) {
        if (t < off) s[t] += s[t + off];
        __syncthreads();
    }
    if (t == 0) bt[b] = s[0];
}

// ------- per-(bucket,block) bases + bucket bases -------
__global__ __launch_bounds__(256) void k_scanB3(const int* __restrict__ bh,
                                                const int* __restrict__ bt,
                                                int* __restrict__ bb,
                                                int* __restrict__ btxg) {
    __shared__ int sA[256], ex[256], sB[256];
    int b = blockIdx.x, t = threadIdx.x;
    int v = (t < NBUK) ? bt[t] : 0;
    sA[t] = v;
    __syncthreads();
    for (int off = 1; off < 256; off <<= 1) {
        int x = (t >= off) ? sA[t - off] : 0;
        __syncthreads();
        sA[t] += x;
        __syncthreads();
    }
    ex[t] = sA[t] - v;
    __syncthreads();
    int btx_b = ex[b];
    int w = bh[t * NBUK + b];
    sB[t] = w;
    __syncthreads();
    for (int off = 1; off < 256; off <<= 1) {
        int x = (t >= off) ? sB[t - off] : 0;
        __syncthreads();
        sB[t] += x;
        __syncthreads();
    }
    bb[b * SB + t] = btx_b + sB[t] - w;
    if (t == 0) btxg[b] = btx_b;
    if (b == 0 && t == 0) btxg[NBUK] = NE;
}

// ------- scatter edges into bucket regions via LDS cursors -------
__global__ __launch_bounds__(512) void k_scatterB(const int* __restrict__ ei,
                                                  const int* __restrict__ flag,
                                                  const int* __restrict__ bb,
                                                  uint* __restrict__ csr) {
    __shared__ int cur[NBUK];
    int blk = blockIdx.x, t = threadIdx.x;
    for (int i = t; i < NBUK; i += 512) cur[i] = bb[i * SB + blk];
    __syncthreads();
    int is64 = *flag;
    int e0 = blk * EPB;
    for (int i = t; i < EPB; i += 512) {
        int e = e0 + i;
        int d = ld_dst(ei, is64, e);
        int s = ld_src(ei, is64, e);
        int pos = atomicAdd(&cur[d >> 8], 1);
        csr[pos] = ((uint)(d & (BKN - 1)) << 16) | (uint)s;
    }
}

// ------- per-bucket compaction + rowstart + dis (all block-local) -------
__global__ __launch_bounds__(256) void k_sortb(const int* __restrict__ btxg,
                                               uint* __restrict__ csr,
                                               int* __restrict__ rowstart,
                                               float* __restrict__ dis) {
    __shared__ uint ent[SORTCAP];
    __shared__ int cnt2[BKN], exs[BKN], cur[BKN];
    int b = blockIdx.x, t = threadIdx.x;
    int base = btxg[b];
    int cntE = btxg[b + 1] - base;
    if (cntE > SORTCAP) cntE = SORTCAP;  // statistically impossible
    cnt2[t] = 0;
    __syncthreads();
    for (int i = t; i < cntE; i += 256) {
        uint v = csr[base + i];
        ent[i] = v;
        atomicAdd(&cnt2[v >> 16], 1);
    }
    __syncthreads();
    int v = cnt2[t];
    exs[t] = v;
    __syncthreads();
    for (int off = 1; off < 256; off <<= 1) {
        int x = (t >= off) ? exs[t - off] : 0;
        __syncthreads();
        exs[t] += x;
        __syncthreads();
    }
    int excl = exs[t] - v;
    int n = b * BKN + t;
    if (n < NN) {
        rowstart[n] = base + excl;
        dis[n] = rsqrtf((float)v + 1.0f);
    }
    if (b == NBUK - 1 && t == 0) rowstart[NN] = NE;
    cur[t] = excl;
    __syncthreads();
    for (int i = t; i < cntE; i += 256) {
        uint v2 = ent[i];
        int p = atomicAdd(&cur[v2 >> 16], 1);
        csr[base + p] = v2 & 0xFFFFu;
    }
}

// ---------------- BN constants prep ----------------
__global__ void k_bnprep(const float* __restrict__ b1, const float* __restrict__ g1,
                         const float* __restrict__ bb1, const float* __restrict__ m1,
                         const float* __restrict__ v1, const float* __restrict__ b2,
                         const float* __restrict__ g2, const float* __restrict__ bb2,
                         const float* __restrict__ m2, const float* __restrict__ v2,
                         const float* __restrict__ b3, const float* __restrict__ g3,
                         const float* __restrict__ bb3, const float* __restrict__ m3,
                         const float* __restrict__ v3, float* __restrict__ sc,
                         float* __restrict__ sh) {
    int t = threadIdx.x;
    if (t < F1) {
        float s = g1[t] * rsqrtf(v1[t] + EPSL);
        sc[t] = s;
        sh[t] = bb1[t] - m1[t] * s + b1[t] * s;
    } else if (t < F1 + F2) {
        int f = t - F1;
        float s = g2[f] * rsqrtf(v2[f] + EPSL);
        sc[t] = s;
        sh[t] = bb2[f] - m2[f] * s + b2[f] * s;
    } else if (t < F1 + F2 + F3) {
        int f = t - F1 - F2;
        float s = g3[f] * rsqrtf(v3[f] + EPSL);
        sc[t] = s;
        sh[t] = bb3[f] - m3[f] * s + b3[f] * s;
    }
}

// ---------------- W1 -> hi/lo bf16 fragments in MFMA order ----------------
__global__ void k_prepW(const float* __restrict__ W1, ushort* __restrict__ Wh,
                        ushort* __restrict__ Wl) {
    int gid = blockIdx.x * 256 + threadIdx.x;
    if (gid >= 3072) return;
    int l = gid & 63;
    int sw = gid >> 6;
    int s = sw & 7;
    int w = sw >> 3;
    int col = w * 16 + (l & 15);
    int kbase = s * 32 + (l >> 4) * 8;
    ushort hi[8], lo[8];
#pragma unroll
    for (int j = 0; j < 8; j++) {
        float v = W1[(size_t)(kbase + j) * F1 + col];
        ushort h = f2b(v);
        hi[j] = h;
        lo[j] = f2b(v - b2f(h));
    }
    *(uint4*)&Wh[(size_t)gid * 8] = *(uint4*)hi;
    *(uint4*)&Wl[(size_t)gid * 8] = *(uint4*)lo;
}

// ------- GEMM1: fused LN(stats in-kernel) @ W1 via split-bf16 MFMA, ·dis ------
__global__ __launch_bounds__(384) void k_gemm1m(
    const float* __restrict__ x, const float* __restrict__ dis,
    const float* __restrict__ ln_g, const float* __restrict__ ln_b,
    const ushort* __restrict__ Wh, const ushort* __restrict__ Wl,
    ushort* __restrict__ outb) {
    __shared__ ushort Ah[1024 * 8];  // 16KB, xor-swizzled
    __shared__ ushort Al[1024 * 8];  // 16KB
    int tid = threadIdx.x;
    int l = tid & 63;
    int w = tid >> 6;
    int brow = blockIdx.x * 32;

    bf16x8 Bh[8], Bl[8];
#pragma unroll
    for (int s = 0; s < 8; s++) {
        int gid = (w * 8 + s) * 64 + l;
        Bh[s] = *(const bf16x8*)&Wh[(size_t)gid * 8];
        Bl[s] = *(const bf16x8*)&Wl[(size_t)gid * 8];
    }

    for (int t = tid; t < 1024; t += 384) {
        int r = t >> 5;
        int c = t & 31;
        int row = brow + r;
        float4 v0 = make_float4(0.f, 0.f, 0.f, 0.f), v1 = v0;
        if (row < NN) {
            const float4* xp = (const float4*)(x + (size_t)row * DIN + c * 8);
            v0 = xp[0];
            v1 = xp[1];
        }
        float s = v0.x + v0.y + v0.z + v0.w + v1.x + v1.y + v1.z + v1.w;
        float q = v0.x * v0.x + v0.y * v0.y + v0.z * v0.z + v0.w * v0.w +
                  v1.x * v1.x + v1.y * v1.y + v1.z * v1.z + v1.w * v1.w;
#pragma unroll
        for (int off = 1; off < 32; off <<= 1) {
            s += __shfl_xor(s, off);
            q += __shfl_xor(q, off);
        }
        float m = s * (1.f / 256.f);
        float rs = rsqrtf(q * (1.f / 256.f) - m * m + EPSL);
        ushort hi[8], lo[8];
        const float4* gp = (const float4*)(ln_g + c * 8);
        const float4* bp = (const float4*)(ln_b + c * 8);
        float4 g0 = gp[0], g1 = gp[1];
        float4 b0 = bp[0], b1 = bp[1];
        float vals[8];
        vals[0] = (v0.x - m) * rs * g0.x + b0.x;
        vals[1] = (v0.y - m) * rs * g0.y + b0.y;
        vals[2] = (v0.z - m) * rs * g0.z + b0.z;
        vals[3] = (v0.w - m) * rs * g0.w + b0.w;
        vals[4] = (v1.x - m) * rs * g1.x + b1.x;
        vals[5] = (v1.y - m) * rs * g1.y + b1.y;
        vals[6] = (v1.z - m) * rs * g1.z + b1.z;
        vals[7] = (v1.w - m) * rs * g1.w + b1.w;
#pragma unroll
        for (int j = 0; j < 8; j++) {
            ushort h = f2b(vals[j]);
            hi[j] = h;
            lo[j] = f2b(vals[j] - b2f(h));
        }
        int sidx = c >> 2, lh = c & 3, rg = r >> 4;
        int slot = (rg * 8 + sidx) * 64 + lh * 16 + (r & 15);
        int byte_off = (slot * 16) ^ ((c & 7) << 4);
        *(uint4*)((char*)Ah + byte_off) = *(uint4*)hi;
        *(uint4*)((char*)Al + byte_off) = *(uint4*)lo;
    }
    __syncthreads();

    f32x4 acc0 = {0.f, 0.f, 0.f, 0.f}, acc1 = {0.f, 0.f, 0.f, 0.f};
#pragma unroll
    for (int s = 0; s < 8; s++) {
        int key = ((s * 4 + (l >> 4)) & 7) << 4;
        int b0 = (((0 * 8 + s) * 64 + l) * 16) ^ key;
        int b1 = (((1 * 8 + s) * 64 + l) * 16) ^ key;
        bf16x8 ah0 = *(const bf16x8*)((const char*)Ah + b0);
        bf16x8 al0 = *(const bf16x8*)((const char*)Al + b0);
        bf16x8 ah1 = *(const bf16x8*)((const char*)Ah + b1);
        bf16x8 al1 = *(const bf16x8*)((const char*)Al + b1);
        acc0 = __builtin_amdgcn_mfma_f32_16x16x32_bf16(al0, Bh[s], acc0, 0, 0, 0);
        acc0 = __builtin_amdgcn_mfma_f32_16x16x32_bf16(ah0, Bl[s], acc0, 0, 0, 0);
        acc0 = __builtin_amdgcn_mfma_f32_16x16x32_bf16(ah0, Bh[s], acc0, 0, 0, 0);
        acc1 = __builtin_amdgcn_mfma_f32_16x16x32_bf16(al1, Bh[s], acc1, 0, 0, 0);
        acc1 = __builtin_amdgcn_mfma_f32_16x16x32_bf16(ah1, Bl[s], acc1, 0, 0, 0);
        acc1 = __builtin_amdgcn_mfma_f32_16x16x32_bf16(ah1, Bh[s], acc1, 0, 0, 0);
    }

    int colg = w * 16 + (l & 15);
    int rbase = (l >> 4) * 4;
#pragma unroll
    for (int i = 0; i < 4; i++) {
        int row0 = brow + rbase + i;
        if (row0 < NN) outb[(size_t)row0 * F1 + colg] = f2b(acc0[i] * dis[row0]);
        int row1 = brow + 16 + rbase + i;
        if (row1 < NN) outb[(size_t)row1 * F1 + colg] = f2b(acc1[i] * dis[row1]);
    }
}

// ---------------- GEMM2: a1[NN,96] @ W2[96,48] -> bf16·dis ----------------
__global__ __launch_bounds__(256) void k_gemm2(const float* __restrict__ A,
                                               const float* __restrict__ W,
                                               const float* __restrict__ dis,
                                               ushort* __restrict__ outb) {
    __shared__ float At[F1][68];
    __shared__ float Ws[F1][F2];
    int tid = threadIdx.x;
    int brow = blockIdx.x * 64;
#pragma unroll
    for (int i = 0; i < 24; i++) {
        int idx = tid + i * 256;
        int r = idx / F1;
        int kk = idx % F1;
        int row = brow + r;
        At[kk][r] = (row < NN) ? A[(size_t)row * F1 + kk] : 0.f;
    }
#pragma unroll
    for (int i = 0; i < 18; i++) {
        int idx = tid + i * 256;
        Ws[idx / F2][idx % F2] = W[idx];
    }
    __syncthreads();
    int rg = tid >> 4;
    int cg = tid & 15;
    float acc[4][3] = {};
#pragma unroll 4
    for (int k = 0; k < F1; k++) {
        float4 a = *(const float4*)&At[k][rg * 4];
        float b[3];
        b[0] = Ws[k][cg * 3];
        b[1] = Ws[k][cg * 3 + 1];
        b[2] = Ws[k][cg * 3 + 2];
#pragma unroll
        for (int j = 0; j < 3; j++) {
            acc[0][j] += a.x * b[j];
            acc[1][j] += a.y * b[j];
            acc[2][j] += a.z * b[j];
            acc[3][j] += a.w * b[j];
        }
    }
#pragma unroll
    for (int i = 0; i < 4; i++) {
        int row = brow + rg * 4 + i;
        if (row < NN) {
            float dsc = dis[row];
            ushort* o = outb + (size_t)row * F2 + cg * 3;
#pragma unroll
            for (int j = 0; j < 3; j++) o[j] = f2b(acc[i][j] * dsc);
        }
    }
}

// ---------------- GEMM3: a2[NN,48] @ W3[48,24] -> bf16·dis ----------------
__global__ __launch_bounds__(256) void k_gemm3(const float* __restrict__ A,
                                               const float* __restrict__ W,
                                               const float* __restrict__ dis,
                                               ushort* __restrict__ outb) {
    __shared__ float At[F2][132];
    __shared__ float Ws[F2][F3];
    int tid = threadIdx.x;
    int brow = blockIdx.x * 128;
#pragma unroll
    for (int i = 0; i < 24; i++) {
        int idx = tid + i * 256;
        int r = idx / F2;
        int kk = idx % F2;
        int row = brow + r;
        At[kk][r] = (row < NN) ? A[(size_t)row * F2 + kk] : 0.f;
    }
#pragma unroll
    for (int i = 0; i < 5; i++) {
        int idx = tid + i * 256;
        if (idx < F2 * F3) Ws[idx / F3][idx % F3] = W[idx];
    }
    __syncthreads();
    int rg = tid >> 3;
    int cg = tid & 7;
    float acc[4][3] = {};
#pragma unroll 4
    for (int k = 0; k < F2; k++) {
        float4 a = *(const float4*)&At[k][rg * 4];
        float b[3];
        b[0] = Ws[k][cg * 3];
        b[1] = Ws[k][cg * 3 + 1];
        b[2] = Ws[k][cg * 3 + 2];
#pragma unroll
        for (int j = 0; j < 3; j++) {
            acc[0][j] += a.x * b[j];
            acc[1][j] += a.y * b[j];
            acc[2][j] += a.z * b[j];
            acc[3][j] += a.w * b[j];
        }
    }
#pragma unroll
    for (int i = 0; i < 4; i++) {
        int row = brow + rg * 4 + i;
        if (row < NN) {
            float dsc = dis[row];
            ushort* o = outb + (size_t)row * F3 + cg * 3;
#pragma unroll
            for (int j = 0; j < 3; j++) o[j] = f2b(acc[i][j] * dsc);
        }
    }
}

// ----- CSR gather agg (bf16 pre-scaled src) + self + ·dis + BN + ReLU -----
template <int F4>
__global__ __launch_bounds__(256) void k_agg(const ushort* __restrict__ hb,
                                             const uint* __restrict__ csr,
                                             const int* __restrict__ rowstart,
                                             const float* __restrict__ dis,
                                             const float* __restrict__ bnsc,
                                             const float* __restrict__ bnsh,
                                             float4* __restrict__ hout) {
    int t = blockIdx.x * blockDim.x + threadIdx.x;
    if (t >= NN * F4) return;
    int n = t / F4;
    int q = t - n * F4;
    const uint2* hrow = (const uint2*)hb;
    int e0 = rowstart[n], e1 = rowstart[n + 1];
    float4 acc = make_float4(0.f, 0.f, 0.f, 0.f);
    int e = e0;
    for (; e + 4 <= e1; e += 4) {
        uint s0 = csr[e + 0], s1 = csr[e + 1], s2 = csr[e + 2], s3 = csr[e + 3];
        uint2 u0 = hrow[(size_t)s0 * F4 + q];
        uint2 u1 = hrow[(size_t)s1 * F4 + q];
        uint2 u2 = hrow[(size_t)s2 * F4 + q];
        uint2 u3 = hrow[(size_t)s3 * F4 + q];
        float4 h0 = unpk(u0), h1 = unpk(u1), h2 = unpk(u2), h3 = unpk(u3);
        acc.x += h0.x + h1.x + h2.x + h3.x;
        acc.y += h0.y + h1.y + h2.y + h3.y;
        acc.z += h0.z + h1.z + h2.z + h3.z;
        acc.w += h0.w + h1.w + h2.w + h3.w;
    }
    for (; e < e1; e++) {
        float4 hv = unpk(hrow[(size_t)csr[e] * F4 + q]);
        acc.x += hv.x;
        acc.y += hv.y;
        acc.z += hv.z;
        acc.w += hv.w;
    }
    float d = dis[n];
    float4 hs = unpk(hrow[(size_t)n * F4 + q]);
    float ax = (acc.x + hs.x) * d;
    float ay = (acc.y + hs.y) * d;
    float az = (acc.z + hs.z) * d;
    float aw = (acc.w + hs.w) * d;
    const float4 sc = *(const float4*)&bnsc[q * 4];
    const float4 sh = *(const float4*)&bnsh[q * 4];
    float4 o;
    o.x = fmaxf(ax * sc.x + sh.x, 0.f);
    o.y = fmaxf(ay * sc.y + sh.y, 0.f);
    o.z = fmaxf(az * sc.z + sh.z, 0.f);
    o.w = fmaxf(aw * sc.w + sh.w, 0.f);
    hout[t] = o;
}

// ---------------- classifier: fc1 + LN + relu + fc2 ----------------
__global__ __launch_bounds__(256) void k_cls(const float* __restrict__ h,
                                             const float* __restrict__ fc1W,
                                             const float* __restrict__ fc1b,
                                             const float* __restrict__ lng,
                                             const float* __restrict__ lnb,
                                             const float* __restrict__ fc2W,
                                             const float* __restrict__ fc2b,
                                             float* __restrict__ out) {
    __shared__ float sW1[24 * 12], sW2[12 * 8], sb1[12], sg[12], sb[12], sb2[8];
    int tid = threadIdx.x;
    for (int i = tid; i < 288; i += 256) sW1[i] = fc1W[i];
    if (tid < 96) sW2[tid] = fc2W[tid];
    if (tid < 12) {
        sb1[tid] = fc1b[tid];
        sg[tid] = lng[tid];
        sb[tid] = lnb[tid];
    }
    if (tid < 8) sb2[tid] = fc2b[tid];
    __syncthreads();
    int n = blockIdx.x * blockDim.x + tid;
    if (n >= NN) return;
    float hv[24];
    const float4* hp = (const float4*)(h + (size_t)n * 24);
#pragma unroll
    for (int i = 0; i < 6; i++) {
        float4 v = hp[i];
        hv[i * 4] = v.x;
        hv[i * 4 + 1] = v.y;
        hv[i * 4 + 2] = v.z;
        hv[i * 4 + 3] = v.w;
    }
    float z[12];
#pragma unroll
    for (int j = 0; j < 12; j++) {
        float a = sb1[j];
#pragma unroll
        for (int k = 0; k < 24; k++) a += hv[k] * sW1[k * 12 + j];
        z[j] = a;
    }
    float s = 0.f, q = 0.f;
#pragma unroll
    for (int j = 0; j < 12; j++) {
        s += z[j];
        q += z[j] * z[j];
    }
    float m = s * (1.f / 12.f);
    float var = q * (1.f / 12.f) - m * m;
    float rs = rsqrtf(var + EPSL);
#pragma unroll
    for (int j = 0; j < 12; j++) z[j] = fmaxf((z[j] - m) * rs * sg[j] + sb[j], 0.f);
    float o[8];
#pragma unroll
    for (int c = 0; c < 8; c++) {
        float a = sb2[c];
#pragma unroll
        for (int j = 0; j < 12; j++) a += z[j] * sW2[j * 8 + c];
        o[c] = a;
    }
    float4* op = (float4*)(out + (size_t)n * 8);
    op[0] = make_float4(o[0], o[1], o[2], o[3]);
    op[1] = make_float4(o[4], o[5], o[6], o[7]);
}

// ---------------- launch ----------------
extern "C" void kernel_launch(void* const* d_in, const int* in_sizes, int n_in,
                              void* d_out, int out_size, void* d_ws, size_t ws_size,
                              hipStream_t stream) {
    const float* x = (const float*)d_in[0];
    const int* ei = (const int*)d_in[1];
    const float* ln_g = (const float*)d_in[2];
    const float* ln_b = (const float*)d_in[3];
    const float* W1 = (const float*)d_in[4];
    const float* b1 = (const float*)d_in[5];
    const float* bn1_g = (const float*)d_in[6];
    const float* bn1_b = (const float*)d_in[7];
    const float* bn1_m = (const float*)d_in[8];
    const float* bn1_v = (const float*)d_in[9];
    const float* W2 = (const float*)d_in[10];
    const float* b2 = (const float*)d_in[11];
    const float* bn2_g = (const float*)d_in[12];
    const float* bn2_b = (const float*)d_in[13];
    const float* bn2_m = (const float*)d_in[14];
    const float* bn2_v = (const float*)d_in[15];
    const float* W3 = (const float*)d_in[16];
    const float* b3 = (const float*)d_in[17];
    const float* bn3_g = (const float*)d_in[18];
    const float* bn3_b = (const float*)d_in[19];
    const float* bn3_m = (const float*)d_in[20];
    const float* bn3_v = (const float*)d_in[21];
    const float* fc1_W = (const float*)d_in[22];
    const float* fc1_b = (const float*)d_in[23];
    const float* lnc_g = (const float*)d_in[24];
    const float* lnc_b = (const float*)d_in[25];
    const float* fc2_W = (const float*)d_in[26];
    const float* fc2_b = (const float*)d_in[27];

    char* w = (char*)d_ws;
    auto alloc = [&](size_t bytes) {
        char* p = w;
        w += (bytes + 255) & ~(size_t)255;
        return p;
    };
    int* flag = (int*)alloc(4);
    int* bh = (int*)alloc((size_t)SB * NBUK * 4);  // per-block bucket hist
    int* bt = (int*)alloc(NBUK * 4);
    int* bb = (int*)alloc((size_t)NBUK * SB * 4);  // per-(bucket,block) bases
    int* btxg = (int*)alloc((NBUK + 1) * 4);
    int* rowstart = (int*)alloc((NN + 1) * 4);
    float* dis = (float*)alloc(NN * 4);
    float* bnsc = (float*)alloc(1024);
    float* bnsh = (float*)alloc(1024);
    uint* csr = (uint*)alloc((size_t)NE * 4);
    float* bufA = (float*)alloc((size_t)NN * F1 * 4);  // fp32 agg outputs
    ushort* hb = (ushort*)alloc((size_t)NN * F1 * 2);  // bf16 gemm outputs (·dis)
    ushort* Wh = (ushort*)alloc(3072 * 8 * 2);
    ushort* Wl = (ushort*)alloc(3072 * 8 * 2);

    k_detect<<<1, 64, 0, stream>>>(ei, flag);
    k_histB<<<SB, 512, 0, stream>>>(ei, flag, bh);
    k_scanB1<<<NBUK, 256, 0, stream>>>(bh, bt);
    k_scanB3<<<NBUK, 256, 0, stream>>>(bh, bt, bb, btxg);
    k_scatterB<<<SB, 512, 0, stream>>>(ei, flag, bb, csr);
    k_sortb<<<NBUK, 256, 0, stream>>>(btxg, csr, rowstart, dis);
    k_bnprep<<<1, 256, 0, stream>>>(b1, bn1_g, bn1_b, bn1_m, bn1_v, b2, bn2_g, bn2_b,
                                    bn2_m, bn2_v, b3, bn3_g, bn3_b, bn3_m, bn3_v, bnsc,
                                    bnsh);
    k_prepW<<<12, 256, 0, stream>>>(W1, Wh, Wl);
    k_gemm1m<<<(NN + 31) / 32, 384, 0, stream>>>(x, dis, ln_g, ln_b, Wh, Wl, hb);
    k_agg<24><<<(NN * 24 + 255) / 256, 256, 0, stream>>>(hb, csr, rowstart, dis, bnsc,
                                                         bnsh, (float4*)bufA);
    k_gemm2<<<(NN + 63) / 64, 256, 0, stream>>>(bufA, W2, dis, hb);
    k_agg<12><<<(NN * 12 + 255) / 256, 256, 0, stream>>>(
        hb, csr, rowstart, dis, bnsc + F1, bnsh + F1, (float4*)bufA);
    k_gemm3<<<(NN + 127) / 128, 256, 0, stream>>>(bufA, W3, dis, hb);
    k_agg<6><<<(NN * 6 + 255) / 256, 256, 0, stream>>>(
        hb, csr, rowstart, dis, bnsc + F1 + F2, bnsh + F1 + F2, (float4*)bufA);
    k_cls<<<(NN + 255) / 256, 256, 0, stream>>>(bufA, fc1_W, fc1_b, lnc_g, lnc_b, fc2_W,
                                                fc2_b, (float*)d_out);
}